// Round 2
// baseline (8859.751 us; speedup 1.0000x reference)
//
#include <hip/hip_runtime.h>

typedef unsigned short u16;
typedef __bf16 v8bf __attribute__((ext_vector_type(8)));
typedef float f32x4 __attribute__((ext_vector_type(4)));
typedef u16 u16x4 __attribute__((ext_vector_type(4)));

#define H5 1280
#define TT 512
#define NBLK 80
#define SPL 81920  // u16 elements per split buffer (64*1280)

// ws layout (bytes)
#define OFF_W0 0
#define OFF_W1 3276800
#define OFF_W2 6553600
#define OFF_HS 9830400   // u16 [2][3][64][1280] ping-pong x 3 splits
#define OFF_WIN 10813440 // float [4][256]
#define OFF_CNT 10817536 // barrier counter

#define MFMA(a, b, c) __builtin_amdgcn_mfma_f32_16x16x32_bf16(a, b, c, 0, 0, 0)

__device__ __forceinline__ float htanh_(float x) {
  return fminf(fmaxf(x, 1e-10f), 1.0f);
}
__device__ __forceinline__ u16 f2b(float f) {
  unsigned u = __float_as_uint(f);
  return (u16)((u + 0x7fffu + ((u >> 16) & 1u)) >> 16);  // RNE
}
__device__ __forceinline__ float b2f(u16 b) {
  return __uint_as_float(((unsigned)b) << 16);
}

// ---------------- prep: effective W_rec, 3-way bf16 split -------------------
__global__ void build_w(const float* __restrict__ w_str2snr, const float* __restrict__ w_m12m1,
                        const float* __restrict__ w_m12str, const float* __restrict__ w_thal2m1,
                        const float* __restrict__ w_m12thal, const float* __restrict__ w_thal2str,
                        const float* __restrict__ w_str2stn, const float* __restrict__ w_snr2thal,
                        const float* __restrict__ fixedw, u16* __restrict__ W0,
                        u16* __restrict__ W1, u16* __restrict__ W2) {
  int idx = blockIdx.x * 256 + threadIdx.x;  // j*1280 + k
  if (idx >= H5 * H5) return;
  int j = idx / H5, k = idx - j * H5;
  int jr = j >> 8, kr = k >> 8, kk = k & 255;
  int o = (j & 255) * 256 + kk;
  float w = 0.0f;
  if (jr == 0) {
    if (kr == 0) w = -fixedw[o];  // str2str_mask==0 -> -(fixed)
    else if (kr == 3) w = htanh_(w_thal2str[o]);
    else if (kr == 4) w = (kk < 180) ? htanh_(w_m12str[o]) : 0.0f;  // n_inhib=76
  } else if (jr == 1) {
    if (kr == 0) w = (kk >= 128) ? htanh_(w_str2stn[o]) : 0.0f;
  } else if (jr == 2) {
    if (kr == 0) w = (kk < 128) ? -htanh_(w_str2snr[o]) : 0.0f;
    else if (kr == 1) w = -htanh_(w_str2stn[o]);  // faithful: str2stn weight
  } else if (jr == 3) {
    if (kr == 2) w = -htanh_(w_snr2thal[o]);
    else if (kr == 4) w = htanh_(w_m12thal[o]);
  } else {
    if (kr == 3) w = htanh_(w_thal2m1[o]);
    else if (kr == 4) w = (kk < 180) ? htanh_(w_m12m1[o]) : -htanh_(w_m12m1[o]);
  }
  u16 c0 = f2b(w);  float r1 = w - b2f(c0);
  u16 c1 = f2b(r1); float r2 = r1 - b2f(c1);
  u16 c2 = f2b(r2);
  W0[idx] = c0; W1[idx] = c1; W2[idx] = c2;
}

// ---------------- prep: mean/std out, h0 splits, Win ------------------------
__global__ void build_misc(const float* __restrict__ hn, const float* __restrict__ inp_weight,
                           const float* __restrict__ mean_b, const float* __restrict__ std_b,
                           float* __restrict__ out, u16* __restrict__ hs, float* __restrict__ Win) {
  int gid = blockIdx.x * 256 + threadIdx.x;
  if (gid < 65536) {
    out[gid] = (gid < 32768) ? mean_b[0] : fminf(10.0f, fmaxf(-5.0f, std_b[0]));
  } else if (gid < 65536 + SPL) {
    int i = gid - 65536;
    float v = hn[i];
    u16 c0 = f2b(v);  float r1 = v - b2f(c0);
    u16 c1 = f2b(r1); float r2 = r1 - b2f(c1);
    u16 c2 = f2b(r2);
    hs[i] = c0; hs[SPL + i] = c1; hs[2 * SPL + i] = c2;
  } else if (gid < 65536 + SPL + 1024) {
    int i = gid - 65536 - SPL;
    Win[i] = htanh_(inp_weight[(i >> 8) * H5 + 768 + (i & 255)]);
  }
}

// ---------------- shared per-tile machinery ---------------------------------
__device__ __forceinline__ void tile_kb(int r, int (&kb)[3], int (&nch)[3]) {
  if (r == 0)      { kb[0] = 0;   nch[0] = 8; kb[1] = 768;  nch[1] = 8; kb[2] = 1024; nch[2] = 8; }
  else if (r == 1) { kb[0] = 128; nch[0] = 4; kb[1] = 0;    nch[1] = 0; kb[2] = 0;    nch[2] = 0; }
  else if (r == 2) { kb[0] = 0;   nch[0] = 4; kb[1] = 256;  nch[1] = 8; kb[2] = 0;    nch[2] = 0; }
  else if (r == 3) { kb[0] = 512; nch[0] = 8; kb[1] = 1024; nch[1] = 8; kb[2] = 0;    nch[2] = 0; }
  else             { kb[0] = 768; nch[0] = 8; kb[1] = 1024; nch[1] = 8; kb[2] = 0;    nch[2] = 0; }
}

__device__ __forceinline__ void load_afr(const u16* __restrict__ W0, const u16* __restrict__ W1,
                                         const u16* __restrict__ W2, int j0, int lr, int lk,
                                         const int (&kb)[3], const int (&nch)[3],
                                         v8bf (&afr)[3][8][3]) {
  const long jrow = (long)(j0 + lr) * H5 + lk;
#pragma unroll
  for (int q = 0; q < 3; ++q) {
    if (nch[q] > 0) {
#pragma unroll
      for (int c = 0; c < 8; ++c) {
        if (c < nch[q]) {
          long off = jrow + kb[q] + c * 32;
          afr[q][c][0] = *(const v8bf*)(W0 + off);
          afr[q][c][1] = *(const v8bf*)(W1 + off);
          afr[q][c][2] = *(const v8bf*)(W2 + off);
        }
      }
    }
  }
}

__device__ __forceinline__ f32x4 do_step(int t, int r, int b, int lk,
                                         const int (&kb)[3], const int (&nch)[3],
                                         const v8bf (&afr)[3][8][3], const float (&winreg)[4][4],
                                         const u16* __restrict__ hs_r,
                                         const float* __restrict__ inp_b, f32x4 hprev) {
  f32x4 a00 = {0.f, 0.f, 0.f, 0.f}, a01 = {0.f, 0.f, 0.f, 0.f};
  f32x4 a10 = {0.f, 0.f, 0.f, 0.f}, a11 = {0.f, 0.f, 0.f, 0.f};
#pragma unroll
  for (int q = 0; q < 3; ++q) {
    if (nch[q] > 0) {
      const u16* hb = hs_r + (long)b * H5 + kb[q] + lk;
#pragma unroll
      for (int c = 0; c < 8; ++c) {
        if (c < nch[q]) {
          v8bf h0 = *(const v8bf*)(hb + c * 32);
          v8bf h1 = *(const v8bf*)(hb + SPL + c * 32);
          v8bf h2 = *(const v8bf*)(hb + 2 * SPL + c * 32);
          if (c & 1) {
            a10 = MFMA(afr[q][c][0], h0, a10);
            a11 = MFMA(afr[q][c][0], h1, a11);
            a10 = MFMA(afr[q][c][1], h0, a10);
            a11 = MFMA(afr[q][c][1], h1, a11);
            a10 = MFMA(afr[q][c][2], h0, a10);
            a11 = MFMA(afr[q][c][0], h2, a11);
          } else {
            a00 = MFMA(afr[q][c][0], h0, a00);
            a01 = MFMA(afr[q][c][0], h1, a01);
            a00 = MFMA(afr[q][c][1], h0, a00);
            a01 = MFMA(afr[q][c][1], h1, a01);
            a00 = MFMA(afr[q][c][2], h0, a00);
            a01 = MFMA(afr[q][c][0], h2, a01);
          }
        }
      }
    }
  }
  f32x4 acc;
#pragma unroll
  for (int rr = 0; rr < 4; ++rr) acc[rr] = (a00[rr] + a01[rr]) + (a10[rr] + a11[rr]);
  if (r == 3) {
    const float* ip = inp_b + t * 4;
    float i0 = ip[0], i1 = ip[1], i2 = ip[2], i3 = ip[3];
#pragma unroll
    for (int rr = 0; rr < 4; ++rr)
      acc[rr] += i0 * winreg[0][rr] + i1 * winreg[1][rr] + i2 * winreg[2][rr] + i3 * winreg[3][rr];
  }
  f32x4 hnew;
#pragma unroll
  for (int rr = 0; rr < 4; ++rr)
    hnew[rr] = fmaxf(0.0f, 0.9f * hprev[rr] + 0.1f * acc[rr]);
  return hnew;
}

__device__ __forceinline__ void store_step(int t, int j0, int b, int hi, f32x4 hnew,
                                           float* __restrict__ rnn_b, u16* __restrict__ hs_w,
                                           float* __restrict__ hn_last) {
  *(f32x4*)(rnn_b + (long)t * H5 + j0 + hi * 4) = hnew;
  if (t < TT - 1) {
    u16x4 s0, s1, s2;
#pragma unroll
    for (int rr = 0; rr < 4; ++rr) {
      float v = hnew[rr];
      u16 c0 = f2b(v);  float r1 = v - b2f(c0);
      u16 c1 = f2b(r1); float r2 = r1 - b2f(c1);
      s0[rr] = c0; s1[rr] = c1; s2[rr] = f2b(r2);
    }
    u16* hw = hs_w + (long)b * H5 + j0 + hi * 4;
    *(u16x4*)(hw) = s0;
    *(u16x4*)(hw + SPL) = s1;
    *(u16x4*)(hw + 2 * SPL) = s2;
  } else {
    float* hl = hn_last + (long)b * H5 + j0 + hi * 4;
#pragma unroll
    for (int rr = 0; rr < 4; ++rr) hl[rr] = hnew[rr];
  }
}

// ---------------- persistent cooperative path -------------------------------
__global__ void __launch_bounds__(256, 1)
rnn_pers(const float* __restrict__ inp, const float* __restrict__ hn,
         const u16* __restrict__ W0, const u16* __restrict__ W1, const u16* __restrict__ W2,
         u16* __restrict__ hs, float* __restrict__ rnn, float* __restrict__ hn_last,
         const float* __restrict__ Win, unsigned* __restrict__ counter) {
  const int lane = threadIdx.x & 63;
  const int lr = lane & 15, hi = lane >> 4, lk = hi * 8;
  const int jt = blockIdx.x;        // 0..79
  const int bt = threadIdx.x >> 6;  // wave id = b-tile
  const int r = jt >> 4;
  const int j0 = jt << 4;
  const int b = (bt << 4) + lr;

  int kb[3], nch[3];
  tile_kb(r, kb, nch);
  v8bf afr[3][8][3];
  load_afr(W0, W1, W2, j0, lr, lk, kb, nch, afr);

  float winreg[4][4];
  if (r == 3) {
#pragma unroll
    for (int i = 0; i < 4; ++i)
#pragma unroll
      for (int rr = 0; rr < 4; ++rr)
        winreg[i][rr] = Win[i * 256 + (j0 - 768) + hi * 4 + rr];
  }

  f32x4 hprev;
  {
    const float* hp = hn + (long)b * H5 + j0 + hi * 4;
#pragma unroll
    for (int rr = 0; rr < 4; ++rr) hprev[rr] = hp[rr];
  }

  float* rnn_b = rnn + (long)b * TT * H5;
  const float* inp_b = inp + (long)b * TT * 4;

  for (int t = 0; t < TT; ++t) {
    const u16* hs_r = hs + (t & 1) * (3 * SPL);
    u16* hs_w = hs + ((t & 1) ^ 1) * (3 * SPL);

    f32x4 hnew = do_step(t, r, b, lk, kb, nch, afr, winreg, hs_r, inp_b, hprev);
    store_step(t, j0, b, hi, hnew, rnn_b, hs_w, hn_last);
    hprev = hnew;

    if (t < TT - 1) {
      __syncthreads();  // all waves' stores drained to L2
      if (threadIdx.x == 0) {
        __hip_atomic_fetch_add(counter, 1u, __ATOMIC_RELEASE, __HIP_MEMORY_SCOPE_AGENT);
        unsigned target = (unsigned)(t + 1) * NBLK;
        while (__hip_atomic_load(counter, __ATOMIC_RELAXED, __HIP_MEMORY_SCOPE_AGENT) < target)
          __builtin_amdgcn_s_sleep(2);
      }
      __syncthreads();
      __builtin_amdgcn_fence(__ATOMIC_ACQUIRE, "agent");
    }
  }
}

// ---------------- fallback path: one kernel per timestep --------------------
__global__ void __launch_bounds__(256, 1)
rnn_step(const float* __restrict__ inp, const float* __restrict__ hn,
         const u16* __restrict__ W0, const u16* __restrict__ W1, const u16* __restrict__ W2,
         u16* __restrict__ hs, float* __restrict__ rnn, float* __restrict__ hn_last,
         const float* __restrict__ Win, int t) {
  const int lane = threadIdx.x & 63;
  const int lr = lane & 15, hi = lane >> 4, lk = hi * 8;
  const int jt = blockIdx.x;
  const int bt = threadIdx.x >> 6;
  const int r = jt >> 4;
  const int j0 = jt << 4;
  const int b = (bt << 4) + lr;

  int kb[3], nch[3];
  tile_kb(r, kb, nch);
  v8bf afr[3][8][3];
  load_afr(W0, W1, W2, j0, lr, lk, kb, nch, afr);

  float winreg[4][4];
  if (r == 3) {
#pragma unroll
    for (int i = 0; i < 4; ++i)
#pragma unroll
      for (int rr = 0; rr < 4; ++rr)
        winreg[i][rr] = Win[i * 256 + (j0 - 768) + hi * 4 + rr];
  }

  f32x4 hprev;
  {
    const float* hp = (t == 0) ? (hn + (long)b * H5 + j0 + hi * 4)
                               : (rnn + ((long)b * TT + (t - 1)) * H5 + j0 + hi * 4);
#pragma unroll
    for (int rr = 0; rr < 4; ++rr) hprev[rr] = hp[rr];
  }

  const u16* hs_r = hs + (t & 1) * (3 * SPL);
  u16* hs_w = hs + ((t & 1) ^ 1) * (3 * SPL);
  float* rnn_b = rnn + (long)b * TT * H5;
  const float* inp_b = inp + (long)b * TT * 4;

  f32x4 hnew = do_step(t, r, b, lk, kb, nch, afr, winreg, hs_r, inp_b, hprev);
  store_step(t, j0, b, hi, hnew, rnn_b, hs_w, hn_last);
}

extern "C" void kernel_launch(void* const* d_in, const int* in_sizes, int n_in,
                              void* d_out, int out_size, void* d_ws, size_t ws_size,
                              hipStream_t stream) {
  const float* inp        = (const float*)d_in[0];
  const float* hn         = (const float*)d_in[1];
  const float* w_str2snr  = (const float*)d_in[3];
  const float* w_m12m1    = (const float*)d_in[4];
  const float* w_m12str   = (const float*)d_in[5];
  const float* w_thal2m1  = (const float*)d_in[6];
  const float* w_m12thal  = (const float*)d_in[7];
  const float* w_thal2str = (const float*)d_in[8];
  const float* w_str2stn  = (const float*)d_in[9];
  const float* w_snr2thal = (const float*)d_in[11];
  const float* inp_weight = (const float*)d_in[12];
  const float* mean_b     = (const float*)d_in[14];
  const float* std_b      = (const float*)d_in[16];
  const float* fixedw     = (const float*)d_in[18];

  char* ws = (char*)d_ws;
  u16* W0 = (u16*)(ws + OFF_W0);
  u16* W1 = (u16*)(ws + OFF_W1);
  u16* W2 = (u16*)(ws + OFF_W2);
  u16* hsb = (u16*)(ws + OFF_HS);
  float* Win = (float*)(ws + OFF_WIN);
  unsigned* cnt = (unsigned*)(ws + OFF_CNT);

  float* out = (float*)d_out;
  float* rnn = out + 65536;
  float* hnl = out + 65536 + 41943040;

  hipMemsetAsync(cnt, 0, 128, stream);
  build_w<<<6400, 256, 0, stream>>>(w_str2snr, w_m12m1, w_m12str, w_thal2m1, w_m12thal,
                                    w_thal2str, w_str2stn, w_snr2thal, fixedw, W0, W1, W2);
  build_misc<<<581, 256, 0, stream>>>(hn, inp_weight, mean_b, std_b, out, hsb, Win);

  void* args[] = {(void*)&inp, (void*)&hn, (void*)&W0, (void*)&W1, (void*)&W2, (void*)&hsb,
                  (void*)&rnn, (void*)&hnl, (void*)&Win, (void*)&cnt};
  hipError_t e = hipLaunchCooperativeKernel((const void*)rnn_pers, dim3(NBLK), dim3(256),
                                            args, 0, stream);
  if (e != hipSuccess) {
    // Fallback: 512 stream-ordered per-step launches (no grid barrier needed).
    for (int t = 0; t < TT; ++t)
      rnn_step<<<NBLK, 256, 0, stream>>>(inp, hn, W0, W1, W2, hsb, rnn, hnl, Win, t);
  }
}